// Round 10
// baseline (120.071 us; speedup 1.0000x reference)
//
#include <hip/hip_runtime.h>

typedef unsigned int   u32;
typedef unsigned short u16;
typedef __attribute__((ext_vector_type(8))) short bf16x8;
typedef __attribute__((ext_vector_type(4))) float f32x4;

// ---------- bf16 helpers ----------
__device__ __forceinline__ float bfs(u16 u) {
  union { u32 i; float f; } v; v.i = ((u32)u) << 16; return v.f;
}
__device__ __forceinline__ u16 f2bf(float f) {
  union { float f; u32 i; } v; v.f = f;
  u32 r = v.i + 0x7fffu + ((v.i >> 16) & 1u);   // RNE
  return (u16)(r >> 16);
}
__device__ __forceinline__ ushort4 f2bf4(float4 v) {
  ushort4 p; p.x = f2bf(v.x); p.y = f2bf(v.y); p.z = f2bf(v.z); p.w = f2bf(v.w);
  return p;
}

// ---------------- Kernel 1: projections + local scan + chunk state ----------
// grid (chunk tt=32, head=16), 256 threads (4 waves). Wave w owns out-group w
// (0=X, 1=B, 2=C, 3=gate). All global stores packed ushort4 via LDS transpose.
// Also: local 64-token logA scan (lexp/linv/dec) and chunk state
// G[bh][jt][c][n] = sum_t X[t][c]*exp(L-l_t)*B[t][n]  (f32).
__global__ __launch_bounds__(256) void k_proj(
    const float* __restrict__ inp,
    const float* __restrict__ W_XBC,  const float* __restrict__ b_XBC,
    const float* __restrict__ W_gate, const float* __restrict__ b_gate,
    const float* __restrict__ W_logA, const float* __restrict__ b_logA,
    const float* __restrict__ Wout, u16* __restrict__ WoutB,
    u16* __restrict__ XsT, u16* __restrict__ BmsT, u16* __restrict__ CmsT,
    u16* __restrict__ gatesP, float* __restrict__ lexp, float* __restrict__ linv,
    float* __restrict__ decArr, float* __restrict__ G)
{
  int tt = blockIdx.x, h = blockIdx.y;
  int tid = threadIdx.x;
  int w = tid >> 6, l = tid & 63, q = l >> 4, lr = l & 15;
  int m0 = tt * 64;
  int b = m0 >> 10, tl0 = m0 & 1023;
  int bh = b * 16 + h;
  int jt = tt & 15;

  __shared__ u16 Xt[64][72];
  __shared__ u16 Wt[256][72];
  __shared__ float wl[64];
  __shared__ float sg[64];

  // Wout f32->bf16, sliced across the 512 blocks (512 float4 each)
  {
    int fid = h * 32 + tt;
    const float4* src = (const float4*)Wout + (size_t)fid * 512;
    ushort4* dst = (ushort4*)WoutB + (size_t)fid * 512;
    for (int i = tid; i < 512; i += 256) dst[i] = f2bf4(src[i]);
  }

  if (tid < 64) wl[tid] = W_logA[h * 64 + tid];
#pragma unroll
  for (int i = 0; i < 4; ++i) {
    int f = tid + 256 * i; int r = f >> 4, cq = f & 15;
    float4 xv = *(const float4*)(inp + (size_t)(m0 + r) * 1024 + h * 64 + 4 * cq);
    *(ushort4*)&Xt[r][4 * cq] = f2bf4(xv);
  }
#pragma unroll
  for (int i = 0; i < 16; ++i) {   // weights (inline f32->bf16)
    int f = tid + 256 * i; int r = f >> 4, cq = f & 15;
    const float* ws = (r < 192) ? (W_XBC + ((size_t)h * 192 + r) * 64)
                                : (W_gate + ((size_t)h * 64 + (r - 192)) * 64);
    *(ushort4*)&Wt[r][4 * cq] = f2bf4(*(const float4*)(ws + 4 * cq));
  }
  __syncthreads();

  bf16x8 af[4][2];
#pragma unroll
  for (int rt = 0; rt < 4; ++rt) {
    af[rt][0] = *(const bf16x8*)&Xt[16 * rt + lr][q * 8];
    af[rt][1] = *(const bf16x8*)&Xt[16 * rt + lr][32 + q * 8];
  }

  f32x4 acc[4][4];
#pragma unroll
  for (int rt = 0; rt < 4; ++rt)
#pragma unroll
    for (int ct = 0; ct < 4; ++ct) acc[rt][ct] = (f32x4){0.f, 0.f, 0.f, 0.f};

#pragma unroll
  for (int ct = 0; ct < 4; ++ct) {
    bf16x8 b0 = *(const bf16x8*)&Wt[64 * w + 16 * ct + lr][q * 8];
    bf16x8 b1 = *(const bf16x8*)&Wt[64 * w + 16 * ct + lr][32 + q * 8];
#pragma unroll
    for (int rt = 0; rt < 4; ++rt) {
      acc[rt][ct] = __builtin_amdgcn_mfma_f32_16x16x32_bf16(af[rt][0], b0, acc[rt][ct], 0, 0, 0);
      acc[rt][ct] = __builtin_amdgcn_mfma_f32_16x16x32_bf16(af[rt][1], b1, acc[rt][ct], 0, 0, 0);
    }
  }

  // ---- local logA + 64-token inclusive scan (wave 0) ----
  if (tid < 64) {
    float a = b_logA[h];
#pragma unroll 16
    for (int k = 0; k < 64; ++k) a += bfs(Xt[tid][k]) * wl[k];
    float lv = a;
#pragma unroll
    for (int off = 1; off < 64; off <<= 1) {
      float n = __shfl_up(lv, off, 64);
      if (tid >= off) lv += n;
    }
    float L = __shfl(lv, 63, 64);
    sg[tid] = __expf(L - lv);
    lexp[(size_t)bh * 1024 + tl0 + tid] = __expf(lv);
    linv[(size_t)bh * 1024 + tl0 + tid] = __expf(-lv);
    if (tid == 63) decArr[bh * 16 + jt] = __expf(L);
  }

  // ---- bias + activation in registers ----
  if (w < 3) {
#pragma unroll
    for (int ct = 0; ct < 4; ++ct) {
      float bias = b_XBC[h * 192 + 64 * w + 16 * ct + lr];
#pragma unroll
      for (int rt = 0; rt < 4; ++rt)
#pragma unroll
        for (int r = 0; r < 4; ++r) {
          float s = acc[rt][ct][r] + bias;
          acc[rt][ct][r] = s / (1.f + __expf(-s));
        }
    }
  } else {
#pragma unroll
    for (int ct = 0; ct < 4; ++ct) {
      float bias = b_gate[h * 64 + 16 * ct + lr];
#pragma unroll
      for (int rt = 0; rt < 4; ++rt)
#pragma unroll
        for (int r = 0; r < 4; ++r) acc[rt][ct][r] += bias;
    }
  }
  __syncthreads();   // Wt frags consumed, sg ready -> reuse Wt as transpose buf

  // ---- transpose into Wt rows [64w, 64w+64) ----
  // w<3: [chan][t]; w==3: [t][chan]
  {
    u16* T = &Wt[64 * w][0];
#pragma unroll
    for (int ct = 0; ct < 4; ++ct)
#pragma unroll
      for (int rt = 0; rt < 4; ++rt)
#pragma unroll
        for (int r = 0; r < 4; ++r) {
          int t = 16 * rt + 4 * q + r, n = 16 * ct + lr;
          u16 v = f2bf(acc[rt][ct][r]);
          if (w < 3) T[n * 72 + t] = v;
          else       T[t * 72 + n] = v;
        }
  }
  __syncthreads();

  // ---- packed global stores ----
  {
#pragma unroll
    for (int i = 0; i < 16; ++i) {
      int s = l + 64 * i; int row = s >> 4, cq = s & 15;
      ushort4 v = *(ushort4*)&Wt[64 * w + row][4 * cq];
      if (w == 0)
        *(ushort4*)(XsT + ((size_t)bh * 64 + row) * 1024 + tl0 + 4 * cq) = v;
      else if (w == 1)
        *(ushort4*)(BmsT + ((size_t)bh * 64 + row) * 1024 + tl0 + 4 * cq) = v;
      else if (w == 2)
        *(ushort4*)(CmsT + ((size_t)bh * 64 + row) * 1024 + tl0 + 4 * cq) = v;
      else
        *(ushort4*)(gatesP + ((size_t)bh * 1024 + tl0 + row) * 64 + 4 * cq) = v;
    }
  }

  // ---- chunk state G[c][n] = sum_t X[t][c]*sg[t]*B[t][n] ----
  {
    bf16x8 a0r = *(const bf16x8*)&Wt[16 * w + lr][q * 8];
    bf16x8 a1r = *(const bf16x8*)&Wt[16 * w + lr][32 + q * 8];
    bf16x8 a0, a1;
#pragma unroll
    for (int jj = 0; jj < 8; ++jj) {
      a0[jj] = (short)f2bf(bfs((u16)a0r[jj]) * sg[q * 8 + jj]);
      a1[jj] = (short)f2bf(bfs((u16)a1r[jj]) * sg[32 + q * 8 + jj]);
    }
    f32x4 gacc[4];
#pragma unroll
    for (int nt = 0; nt < 4; ++nt) {
      gacc[nt] = (f32x4){0.f, 0.f, 0.f, 0.f};
      bf16x8 bb0 = *(const bf16x8*)&Wt[64 + 16 * nt + lr][q * 8];
      bf16x8 bb1 = *(const bf16x8*)&Wt[64 + 16 * nt + lr][32 + q * 8];
      gacc[nt] = __builtin_amdgcn_mfma_f32_16x16x32_bf16(a0, bb0, gacc[nt], 0, 0, 0);
      gacc[nt] = __builtin_amdgcn_mfma_f32_16x16x32_bf16(a1, bb1, gacc[nt], 0, 0, 0);
    }
    float* Gt = G + ((size_t)bh * 16 + jt) * 4096;
#pragma unroll
    for (int nt = 0; nt < 4; ++nt)
#pragma unroll
      for (int r = 0; r < 4; ++r)
        Gt[(16 * w + 4 * q + r) * 64 + 16 * nt + lr] = gacc[nt][r];
  }
}

// ---------------- Kernel 2: diag quadratic + on-the-fly Hpre + C·Hpre --------
// grid (it=16, bh=32), 256 threads. Hpre(it) = sum_{jt<it} (prod dec) G_jt
// computed per block from G (f32) — k_mid eliminated.
__global__ __launch_bounds__(256) void k_ssm2(
    const u16* __restrict__ XsT, const u16* __restrict__ BmsT,
    const u16* __restrict__ CmsT,
    const float* __restrict__ lexp, const float* __restrict__ linv,
    const float* __restrict__ G, const float* __restrict__ decArr,
    const u16* __restrict__ gatesP, u16* __restrict__ Yg)
{
  int it = blockIdx.x, bh = blockIdx.y;
  int b = bh >> 4, h = bh & 15;
  int tid = threadIdx.x;
  int w = tid >> 6, l = tid & 63, q = l >> 4, lr = l & 15;
  int i0 = it * 64;

  __shared__ u16 Cts[64][72];   // [t][n]
  __shared__ u16 Bts[64][72];   // [t][n]
  __shared__ u16 Xts[64][72];   // [c][t]
  __shared__ u16 HTt[64][72];   // [c][n]
  __shared__ u16 Gts[64][72];   // [t][c]
  __shared__ u16 Sts[64][72];
  __shared__ float ref_[64], cef[64], dsm[16];

  const u16* Xb  = XsT  + (size_t)bh * 64 * 1024;
  const u16* BbT = BmsT + (size_t)bh * 64 * 1024;
  const u16* CbT = CmsT + (size_t)bh * 64 * 1024;
  const u16* Gb  = gatesP + ((size_t)bh * 1024 + i0) * 64;
  const float* Gf = G + (size_t)bh * 16 * 4096;

  if (tid < 16) dsm[tid] = decArr[bh * 16 + tid];
  if (tid < 64) {
    ref_[tid] = lexp[(size_t)bh * 1024 + i0 + tid];
    cef[tid]  = linv[(size_t)bh * 1024 + i0 + tid];
  }
#pragma unroll
  for (int i = 0; i < 4; ++i) {
    int f = tid + 256 * i; int r = f >> 4, cq = f & 15;
    *(ushort4*)&Xts[r][4 * cq] = *(const ushort4*)(Xb + (size_t)r * 1024 + i0 + 4 * cq);
    *(ushort4*)&Gts[r][4 * cq] = *(const ushort4*)(Gb + r * 64 + 4 * cq);
    ushort4 bv = *(const ushort4*)(BbT + (size_t)r * 1024 + i0 + 4 * cq);
    Bts[4 * cq + 0][r] = bv.x; Bts[4 * cq + 1][r] = bv.y;
    Bts[4 * cq + 2][r] = bv.z; Bts[4 * cq + 3][r] = bv.w;
    ushort4 cv = *(const ushort4*)(CbT + (size_t)r * 1024 + i0 + 4 * cq);
    Cts[4 * cq + 0][r] = cv.x; Cts[4 * cq + 1][r] = cv.y;
    Cts[4 * cq + 2][r] = cv.z; Cts[4 * cq + 3][r] = cv.w;
  }
  __syncthreads();

  // ---- Hpre on the fly: downward loop, far chunks decay to 0 ----
  {
    float hacc[4][4];
#pragma unroll
    for (int k = 0; k < 4; ++k)
#pragma unroll
      for (int r = 0; r < 4; ++r) hacc[k][r] = 0.f;
    float fdec = 1.f;
    for (int jt = it - 1; jt >= 0; --jt) {
      const float* Gj = Gf + (size_t)jt * 4096 + tid * 4;
#pragma unroll
      for (int k = 0; k < 4; ++k) {
        float4 g4 = *(const float4*)(Gj + 1024 * k);
        hacc[k][0] += fdec * g4.x; hacc[k][1] += fdec * g4.y;
        hacc[k][2] += fdec * g4.z; hacc[k][3] += fdec * g4.w;
      }
      fdec *= dsm[jt];
    }
    int row0 = tid >> 4, colb = (tid & 15) * 4;
#pragma unroll
    for (int k = 0; k < 4; ++k) {
      ushort4 hv;
      hv.x = f2bf(hacc[k][0]); hv.y = f2bf(hacc[k][1]);
      hv.z = f2bf(hacc[k][2]); hv.w = f2bf(hacc[k][3]);
      *(ushort4*)&HTt[row0 + 16 * k][colb] = hv;
    }
  }

  // ---- phase 1: diagonal S tile ----
  bf16x8 ca0 = *(const bf16x8*)&Cts[16 * w + lr][q * 8];
  bf16x8 ca1 = *(const bf16x8*)&Cts[16 * w + lr][32 + q * 8];
#pragma unroll
  for (int ct = 0; ct < 4; ++ct) {
    f32x4 s = (f32x4){0.f, 0.f, 0.f, 0.f};
    bf16x8 b0 = *(const bf16x8*)&Bts[16 * ct + lr][q * 8];
    bf16x8 b1 = *(const bf16x8*)&Bts[16 * ct + lr][32 + q * 8];
    s = __builtin_amdgcn_mfma_f32_16x16x32_bf16(ca0, b0, s, 0, 0, 0);
    s = __builtin_amdgcn_mfma_f32_16x16x32_bf16(ca1, b1, s, 0, 0, 0);
    int jl = 16 * ct + lr;
    float cj = cef[jl];
#pragma unroll
    for (int r = 0; r < 4; ++r) {
      int il = 16 * w + q * 4 + r;
      float v = (jl > il) ? 0.f : s[r] * ref_[il] * cj;
      Sts[il][jl] = f2bf(v);
    }
  }
  __syncthreads();   // covers HTt + Sts before phase 2

  // ---- phase 2: Y = S·X_diag + diag(lexp)·(C·Hpre) ----
  bf16x8 sa0 = *(const bf16x8*)&Sts[16 * w + lr][q * 8];
  bf16x8 sa1 = *(const bf16x8*)&Sts[16 * w + lr][32 + q * 8];
  f32x4 accd[4], acco[4];
#pragma unroll
  for (int ct = 0; ct < 4; ++ct) {
    accd[ct] = (f32x4){0.f, 0.f, 0.f, 0.f};
    acco[ct] = (f32x4){0.f, 0.f, 0.f, 0.f};
    bf16x8 x0 = *(const bf16x8*)&Xts[16 * ct + lr][q * 8];
    bf16x8 x1 = *(const bf16x8*)&Xts[16 * ct + lr][32 + q * 8];
    accd[ct] = __builtin_amdgcn_mfma_f32_16x16x32_bf16(sa0, x0, accd[ct], 0, 0, 0);
    accd[ct] = __builtin_amdgcn_mfma_f32_16x16x32_bf16(sa1, x1, accd[ct], 0, 0, 0);
    bf16x8 h0 = *(const bf16x8*)&HTt[16 * ct + lr][q * 8];
    bf16x8 h1 = *(const bf16x8*)&HTt[16 * ct + lr][32 + q * 8];
    acco[ct] = __builtin_amdgcn_mfma_f32_16x16x32_bf16(ca0, h0, acco[ct], 0, 0, 0);
    acco[ct] = __builtin_amdgcn_mfma_f32_16x16x32_bf16(ca1, h1, acco[ct], 0, 0, 0);
  }

#pragma unroll
  for (int ct = 0; ct < 4; ++ct) {
    int c = 16 * ct + lr;
#pragma unroll
    for (int r = 0; r < 4; ++r) {
      int il = 16 * w + q * 4 + r;
      int tg = i0 + il;
      size_t row = (size_t)(b * 1024 + tg);
      float y = accd[ct][r] + ref_[il] * acco[ct][r];
      float gt = bfs(Gts[il][c]);
      Yg[row * 1024 + h * 64 + c] = f2bf(y * gt);
    }
  }
}

// ---------------- Kernel 3: out = Yg @ W_out^T + b_out — MFMA 64x64 ----------
// grid (32,16), 256 threads — 2 blocks/CU for cross-block barrier overlap.
__global__ __launch_bounds__(256) void k_out(
    const u16* __restrict__ Yg, const u16* __restrict__ WoutB,
    const float* __restrict__ bout, float* __restrict__ out)
{
  int bm = blockIdx.x, bn = blockIdx.y;
  int tid = threadIdx.x;
  int w = tid >> 6, l = tid & 63, q = l >> 4, lr = l & 15;
  int m0 = bm * 64, d0 = bn * 64;

  __shared__ u16 Yt[64][72];
  __shared__ u16 Wt[64][72];

  f32x4 acc[4];
#pragma unroll
  for (int ct = 0; ct < 4; ++ct) acc[ct] = (f32x4){0.f, 0.f, 0.f, 0.f};

  ushort4 py[4], pw[4];
#pragma unroll
  for (int i = 0; i < 4; ++i) {
    int f = tid + 256 * i; int r = f >> 4, cq = f & 15;
    py[i] = *(const ushort4*)(Yg + (size_t)(m0 + r) * 1024 + 4 * cq);
    pw[i] = *(const ushort4*)(WoutB + (size_t)(d0 + r) * 1024 + 4 * cq);
  }

  for (int kt = 0; kt < 16; ++kt) {
    __syncthreads();
#pragma unroll
    for (int i = 0; i < 4; ++i) {
      int f = tid + 256 * i; int r = f >> 4, cq = f & 15;
      *(ushort4*)&Yt[r][4 * cq] = py[i];
      *(ushort4*)&Wt[r][4 * cq] = pw[i];
    }
    __syncthreads();

    if (kt < 15) {
      int k1 = (kt + 1) * 64;
#pragma unroll
      for (int i = 0; i < 4; ++i) {
        int f = tid + 256 * i; int r = f >> 4, cq = f & 15;
        py[i] = *(const ushort4*)(Yg + (size_t)(m0 + r) * 1024 + k1 + 4 * cq);
        pw[i] = *(const ushort4*)(WoutB + (size_t)(d0 + r) * 1024 + k1 + 4 * cq);
      }
    }

    bf16x8 a0 = *(const bf16x8*)&Yt[16 * w + lr][q * 8];
    bf16x8 a1 = *(const bf16x8*)&Yt[16 * w + lr][32 + q * 8];
#pragma unroll
    for (int ct = 0; ct < 4; ++ct) {
      bf16x8 b0 = *(const bf16x8*)&Wt[16 * ct + lr][q * 8];
      bf16x8 b1 = *(const bf16x8*)&Wt[16 * ct + lr][32 + q * 8];
      acc[ct] = __builtin_amdgcn_mfma_f32_16x16x32_bf16(a0, b0, acc[ct], 0, 0, 0);
      acc[ct] = __builtin_amdgcn_mfma_f32_16x16x32_bf16(a1, b1, acc[ct], 0, 0, 0);
    }
  }

#pragma unroll
  for (int ct = 0; ct < 4; ++ct) {
    int d = d0 + 16 * ct + lr;
    float bo = bout[d];
#pragma unroll
    for (int r = 0; r < 4; ++r) {
      int m = m0 + 16 * w + q * 4 + r;
      out[(size_t)m * 1024 + d] = acc[ct][r] + bo;
    }
  }
}

// ---------------- host launcher ----------------
extern "C" void kernel_launch(void* const* d_in, const int* in_sizes, int n_in,
                              void* d_out, int out_size, void* d_ws, size_t ws_size,
                              hipStream_t stream)
{
  const float* inp   = (const float*)d_in[0];
  const float* WlogA = (const float*)d_in[1];
  const float* blogA = (const float*)d_in[2];
  const float* WXBC  = (const float*)d_in[3];
  const float* bXBC  = (const float*)d_in[4];
  const float* Wgate = (const float*)d_in[5];
  const float* bgate = (const float*)d_in[6];
  const float* Wout  = (const float*)d_in[7];
  const float* bout  = (const float*)d_in[8];
  float* out = (float*)d_out;

  const size_t SZ = (size_t)2 * 16 * 1024 * 64;  // 2,097,152 elements
  float* lexp   = (float*)d_ws;                  // 32768 f32
  float* linv   = lexp + 32768;                  // 32768 f32
  float* decA   = linv + 32768;                  // 512 f32
  float* G      = decA + 512;                    // 32*16*4096 f32 = 8 MiB
  u16* base16 = (u16*)(G + (size_t)32 * 16 * 4096);
  u16* XsT    = base16;              // [bh][c][t]   4 MiB
  u16* BmsT   = XsT + SZ;            // [bh][n][t]   4 MiB
  u16* CmsT   = BmsT + SZ;           // [bh][n][t]   4 MiB
  u16* gatesP = CmsT + SZ;           // [bh][t][c]   4 MiB
  u16* Yg     = gatesP + SZ;         // [b,t,d]      4 MiB
  u16* WoutB  = Yg + SZ;             //              2 MiB  (~30.3 MiB total)

  k_proj<<<dim3(32, 16), 256, 0, stream>>>(inp, WXBC, bXBC, Wgate, bgate,
                                           WlogA, blogA, Wout, WoutB,
                                           XsT, BmsT, CmsT, gatesP,
                                           lexp, linv, decA, G);
  k_ssm2<<<dim3(16, 32), 256, 0, stream>>>(XsT, BmsT, CmsT, lexp, linv,
                                           G, decA, gatesP, Yg);
  k_out<<<dim3(32, 16), 256, 0, stream>>>(Yg, WoutB, bout, out);
}